// Round 19
// baseline (108.106 us; speedup 1.0000x reference)
//
#include <hip/hip_runtime.h>
#include <math.h>

#define VOCAB 50000
#define EMBED 128
#define SEQ   200
#define HID   30
#define BATCH 4096

// MODEL (r18 fit): step 852 cyc, VALU 60%, LDS 56% -- neither saturated;
// the serial chain's LDS round-trip (~150 cyc) blocks overlap at 2 waves/SIMD.
// r19: ZERO LDS in the loop. Each 16-lane (row, k-half) group already holds
// its full k-half in registers (lane (j16,p) keeps hreg = h[j16+16p]), so the
// gather is 15 INDEPENDENT v_mov_dpp row_ror:n ops (depth 1 -- r11's serial
// ror chain and r17's LDS+quad hybrid were the failures, not DPP itself).
// k arrival order via runtime probe (same DPP on j16); cross-half partial
// exchange stays r18's probe-selected permlane32_swap. Pad lanes (cols 30,31)
// compute garbage hreg consumed only via wh==0 weights (finite, safe).
// embproj + head byte-frozen.
typedef float4 __attribute__((__may_alias__)) f4ma;
typedef unsigned int uint2v __attribute__((ext_vector_type(2)));

__device__ __forceinline__ float tanh_fast(float x) {
    float e = __expf(2.0f * x);
    return 1.0f - __fdividef(2.0f, e + 1.0f);
}
__device__ __forceinline__ float swz16_f(float x) {   // embproj only
    return __int_as_float(__builtin_amdgcn_ds_swizzle(__float_as_int(x), 0x401F));
}
// immediate DPP within 16-lane rows: row_ror:n = 0x120+n
#define DPPI(x, ctrl) __builtin_amdgcn_update_dpp(0, (x), (ctrl), 0xF, 0xF, false)

// Kernel 1: embP[v][j] = sum_e emb[v][e]*Wx[e][j] + b_rnn[j]
// BYTE-IDENTICAL to r16-r18 (passed 3x). Do not touch.
__global__ __launch_bounds__(256, 2) void embproj_kernel(
    const float* __restrict__ emb, const float* __restrict__ Wx,
    const float* __restrict__ brnn, float* __restrict__ embP)
{
    int tid  = threadIdx.x;
    int wv   = tid >> 6;
    int l    = tid & 63;
    int j16  = l & 15;
    int p    = (l >> 4) & 1;
    int g    = l >> 5;
    int col  = j16 + 16 * g;
    int colc = (col < HID) ? col : (HID - 1);
    int k0   = 64 * p;

    float whx[64];
    #pragma unroll
    for (int i = 0; i < 64; ++i)
        whx[i] = Wx[(k0 + i) * HID + colc];
    float bj = brnn[colc];

    int base = (blockIdx.x * 4 + wv) * 25;

    float4 eA[16], eB[16];
    #define LOADROW(dst, v) { \
        int vc = min((v), VOCAB - 1); \
        const f4ma* e4 = (const f4ma*)(emb + (size_t)vc * EMBED + k0); \
        _Pragma("unroll") \
        for (int q = 0; q < 16; ++q) dst[q] = e4[q]; \
    }
    #define COMPUTE(src, v) { \
        float a0 = 0.f, a1 = 0.f, a2 = 0.f, a3 = 0.f; \
        _Pragma("unroll") \
        for (int q = 0; q < 16; ++q) { \
            a0 += src[q].x * whx[4*q+0]; \
            a1 += src[q].y * whx[4*q+1]; \
            a2 += src[q].z * whx[4*q+2]; \
            a3 += src[q].w * whx[4*q+3]; \
        } \
        float own  = (a0 + a1) + (a2 + a3); \
        float full = bj + (own + swz16_f(own)); \
        if (p == 0 && col < HID && (v) < VOCAB) \
            embP[(size_t)(v) * HID + col] = full; \
    }

    LOADROW(eA, base + 0);
    for (int r = 0; r < 25; r += 2) {
        LOADROW(eB, base + r + 1);
        COMPUTE(eA, base + r);
        LOADROW(eA, base + r + 2);
        COMPUTE(eB, base + r + 1);
    }
    #undef LOADROW
    #undef COMPUTE
}

// Kernel 2: fused RNN recurrence + dense head. ZERO loop LDS.
// Lane bits (r18 mapping): j16 = l&15, row = (l>>4)&1, p = l>>5.
// Own col j = j16+16p; hreg = h[j] of own row, kept in-register.
// Per step: 15x independent v_mov_dpp row_ror (gather own k-half) ->
// 32 FMA (both cols' partials over half p) -> permlane32_swap (partner
// l^32) -> tanh -> hreg. h touches LDS only once, after the loop (head).
__global__ __launch_bounds__(128) void rnn_head_kernel(
    const int* __restrict__ tokens, const float* __restrict__ embP,
    const float* __restrict__ Wh,
    const float* __restrict__ W1, const float* __restrict__ b1,
    const float* __restrict__ W2, const float* __restrict__ b2,
    const float* __restrict__ W3, const float* __restrict__ b3,
    const float* __restrict__ Wo, const float* __restrict__ bo,
    float* __restrict__ out)
{
    __shared__ float hL[4][32];
    __shared__ float d1L[4][128];
    __shared__ float d2L[4][64];

    int tid  = threadIdx.x;
    int wv   = tid >> 6;            // wave 0..1
    int l    = tid & 63;
    int j16  = l & 15;
    int row  = (l >> 4) & 1;        // row within wave (bit 4)
    int p    = l >> 5;              // k-half (bit 5) -> partner = l^32
    int j    = j16 + 16 * p;        // own column
    int rloc = wv * 2 + row;        // row within block, 0..3
    int b    = blockIdx.x * 4 + rloc;

    const int* trow = tokens + (size_t)b * SEQ;
    int jc = (j < HID) ? j : (HID - 1);

    // permlane32_swap direction probe (r18-proven)
    bool useR0;
    {
        unsigned li = (unsigned)l;
        uint2v rp = __builtin_amdgcn_permlane32_swap(li, li, false, false);
        useR0 = (rp[0] == (unsigned)(l ^ 32));
    }

    // DPP arrival probe: slot n holds hreg of the j16 given by ror_n(j16)
    int kq[16];
    kq[0]  = j16;
    kq[1]  = DPPI(j16, 0x121);  kq[2]  = DPPI(j16, 0x122);
    kq[3]  = DPPI(j16, 0x123);  kq[4]  = DPPI(j16, 0x124);
    kq[5]  = DPPI(j16, 0x125);  kq[6]  = DPPI(j16, 0x126);
    kq[7]  = DPPI(j16, 0x127);  kq[8]  = DPPI(j16, 0x128);
    kq[9]  = DPPI(j16, 0x129);  kq[10] = DPPI(j16, 0x12A);
    kq[11] = DPPI(j16, 0x12B);  kq[12] = DPPI(j16, 0x12C);
    kq[13] = DPPI(j16, 0x12D);  kq[14] = DPPI(j16, 0x12E);
    kq[15] = DPPI(j16, 0x12F);

    int cB = j16 + 16;
    float whA[16], whB[16];
    #pragma unroll
    for (int n = 0; n < 16; ++n) {
        int k = 16 * p + kq[n];      // k value arriving in slot n
        whA[n] = (k < HID) ? Wh[k * HID + j16] : 0.0f;
        whB[n] = (k < HID && cB < HID) ? Wh[k * HID + cB] : 0.0f;
    }

    // two-level pipeline: xq[s] = xp for step t+s; tr[s] = token for t+8+s
    float xq[8]; int tr[8];
    #pragma unroll
    for (int s = 0; s < 8; ++s) {
        xq[s] = embP[(size_t)trow[s] * HID + jc];
        tr[s] = trow[8 + s];
    }

    float hreg = 0.0f;   // h[own col]; pad lanes carry garbage (consumed x0)

    for (int t = 0; t < SEQ; t += 8) {
        #pragma unroll
        for (int s = 0; s < 8; ++s) {
            // 15 INDEPENDENT DPP rors: all 16 h values of own k-half
            int hi = __float_as_int(hreg);
            float hv[16];
            hv[0]  = hreg;
            hv[1]  = __int_as_float(DPPI(hi, 0x121));
            hv[2]  = __int_as_float(DPPI(hi, 0x122));
            hv[3]  = __int_as_float(DPPI(hi, 0x123));
            hv[4]  = __int_as_float(DPPI(hi, 0x124));
            hv[5]  = __int_as_float(DPPI(hi, 0x125));
            hv[6]  = __int_as_float(DPPI(hi, 0x126));
            hv[7]  = __int_as_float(DPPI(hi, 0x127));
            hv[8]  = __int_as_float(DPPI(hi, 0x128));
            hv[9]  = __int_as_float(DPPI(hi, 0x129));
            hv[10] = __int_as_float(DPPI(hi, 0x12A));
            hv[11] = __int_as_float(DPPI(hi, 0x12B));
            hv[12] = __int_as_float(DPPI(hi, 0x12C));
            hv[13] = __int_as_float(DPPI(hi, 0x12D));
            hv[14] = __int_as_float(DPPI(hi, 0x12E));
            hv[15] = __int_as_float(DPPI(hi, 0x12F));

            // ring refills (off the critical path)
            float xp = xq[s];
            xq[s] = embP[(size_t)tr[s] * HID + jc];
            int tn = t + 16 + s; tn = (tn < SEQ) ? tn : SEQ - 1;
            tr[s] = trow[tn];

            // both columns' partials over own k-half (4 chains, depth 8)
            float a0=0.f, a1=0.f, b0=0.f, b1=0.f;
            #pragma unroll
            for (int n = 0; n < 16; n += 2) {
                a0 += hv[n]   * whA[n];
                a1 += hv[n+1] * whA[n+1];
                b0 += hv[n]   * whB[n];
                b1 += hv[n+1] * whB[n+1];
            }
            float pA = a0 + a1;            // col j16    , k-half p
            float pB = b0 + b1;            // col j16+16 , k-half p
            float own  = p ? pB : pA;
            float send = p ? pA : pB;      // partner (l^32) needs this
            unsigned si = __float_as_uint(send);
            uint2v sw = __builtin_amdgcn_permlane32_swap(si, si, false, false);
            float recv = __uint_as_float(useR0 ? sw[0] : sw[1]);
            hreg = tanh_fast(xp + (own + recv));
        }
    }

    // stage final h for the head (gated: pad cols must read as 0)
    hL[rloc][j] = (j < HID) ? hreg : 0.0f;
    __builtin_amdgcn_sched_barrier(0);

    // ---- dense head: r16 code verbatim (its own lane mapping) ----
    {
        int half = l >> 5, j32 = l & 31;
        int rh = wv * 2 + half;
        int bB = blockIdx.x * 4 + rh;
        #pragma unroll
        for (int qq = 0; qq < 4; ++qq) {
            int c = j32 + 32 * qq;
            float acc = b1[c];
            #pragma unroll
            for (int k = 0; k < HID; ++k) acc += hL[rh][k] * W1[k * 128 + c];
            d1L[rh][c] = fmaxf(acc, 0.0f);
        }
        #pragma unroll
        for (int qq = 0; qq < 2; ++qq) {
            int c = j32 + 32 * qq;
            float acc = b2[c];
            #pragma unroll 8
            for (int k = 0; k < 128; ++k) acc += d1L[rh][k] * W2[k * 64 + c];
            d2L[rh][c] = fmaxf(acc, 0.0f);
        }
        float acc3 = b3[j32];
        #pragma unroll 8
        for (int k = 0; k < 64; ++k) acc3 += d2L[rh][k] * W3[k * 32 + j32];
        acc3 = fmaxf(acc3, 0.0f);
        float prod = acc3 * Wo[j32];
        #pragma unroll
        for (int m = 16; m > 0; m >>= 1) prod += __shfl_xor(prod, m, 32);
        if (j32 == 0) out[bB] = 1.0f / (1.0f + __expf(-(prod + bo[0])));
    }
}

extern "C" void kernel_launch(void* const* d_in, const int* in_sizes, int n_in,
                              void* d_out, int out_size, void* d_ws, size_t ws_size,
                              hipStream_t stream) {
    (void)in_sizes; (void)n_in; (void)out_size; (void)ws_size;
    const int*   tokens = (const int*)  d_in[0];
    const float* emb    = (const float*)d_in[1];
    const float* Wx     = (const float*)d_in[2];
    const float* Wh     = (const float*)d_in[3];
    const float* brnn   = (const float*)d_in[4];
    const float* W1     = (const float*)d_in[5];
    const float* b1     = (const float*)d_in[6];
    const float* W2     = (const float*)d_in[7];
    const float* b2     = (const float*)d_in[8];
    const float* W3     = (const float*)d_in[9];
    const float* b3     = (const float*)d_in[10];
    const float* Wo     = (const float*)d_in[11];
    const float* bo     = (const float*)d_in[12];
    float* out  = (float*)d_out;
    float* embP = (float*)d_ws;   // 50000*30*4 = 6 MB

    embproj_kernel<<<512, 256, 0, stream>>>(emb, Wx, brnn, embP);
    rnn_head_kernel<<<BATCH / 4, 128, 0, stream>>>(
        tokens, embP, Wh, W1, b1, W2, b2, W3, b3, Wo, bo, out);
}